// Round 7
// baseline (282.045 us; speedup 1.0000x reference)
//
#include <hip/hip_runtime.h>
#include <math.h>

#define BB 32
#define LL 200
#define HH 64
#define HSS 32
#define HB 64
#define NEGV (-4294967295.0f)

typedef __bf16 bf16x8 __attribute__((ext_vector_type(8)));
typedef float f32x4 __attribute__((ext_vector_type(4)));

// ---------------------------------------------------------------------------
// Kernel A: QKV projections into split-head layout  Qs/Ks/Vs [HB][L][HS]
// ---------------------------------------------------------------------------
__global__ __launch_bounds__(64) void proj_kernel(
    const float* __restrict__ q_in, const float* __restrict__ k_in,
    const float* __restrict__ v_in,
    const float* __restrict__ Wq, const float* __restrict__ bq,
    const float* __restrict__ Wk, const float* __restrict__ bk,
    const float* __restrict__ Wv, const float* __restrict__ bv,
    float* __restrict__ Qs, float* __restrict__ Ks, float* __restrict__ Vs)
{
    const int row = blockIdx.x;            // b*L + l
    const int b = row / LL, l = row % LL;
    const int j = threadIdx.x;             // output channel 0..63

    __shared__ float s[3][HH];
    s[0][j] = q_in[row*HH + j];
    s[1][j] = k_in[row*HH + j];
    s[2][j] = v_in[row*HH + j];
    __syncthreads();

    const float* W[3]    = {Wq, Wk, Wv};
    const float* bias[3] = {bq, bk, bv};
    float*       dst[3]  = {Qs, Ks, Vs};

    const int hb  = (j >> 5)*BB + b;                 // head*B + b
    const int idx = (hb*LL + l)*HSS + (j & 31);

    #pragma unroll
    for (int m = 0; m < 3; ++m) {
        float acc = bias[m][j];
        #pragma unroll
        for (int i = 0; i < HH; ++i)
            acc = fmaf(s[m][i], W[m][i*HH + j], acc);
        dst[m][idx] = acc;
    }
}

// ---------------------------------------------------------------------------
// Kernel P: Wt (fp32 [k][n]) -> WtT_bf16 [n][k]  (B-operand, N-major)
// ---------------------------------------------------------------------------
__global__ __launch_bounds__(256) void prep_kernel(
    const float* __restrict__ Wt, unsigned short* __restrict__ WtT)
{
    const int t = blockIdx.x*256 + threadIdx.x;      // t = n*64 + k
    if (t < HH*HH) {
        const int n = t >> 6, k = t & 63;
        const __bf16 h = (__bf16)Wt[k*HH + n];
        WtT[t] = __builtin_bit_cast(unsigned short, h);
    }
}

// ---------------------------------------------------------------------------
// Kernel M: time-bias MLP pre-activations, LOWER TRIANGLE ONLY.
// One wave per (hb, q, 16-key chunk) with chunk-base <= q and row not
// time-masked. No LDS, no barriers: direct global->reg->bf16 A-fragments,
// 8 MFMAs, 16-lane reduce, store raw p into Plog[hb][q][key] (attn region
// of d_out, consumed & overwritten by attn2_kernel).
// ---------------------------------------------------------------------------
__global__ __launch_bounds__(256) void mlp_kernel(
    const float* __restrict__ T,                 // [HB, L, L, H] fp32
    const int*   __restrict__ time_mask,         // [B, L] int32
    const unsigned short* __restrict__ WtT,      // bf16 [n][k]
    const float* __restrict__ bt, const float* __restrict__ Wp,
    float* __restrict__ Plog)                    // [HB, L, L]
{
    const int q  = blockIdx.y;
    const int hb = blockIdx.z;
    const int b  = hb & (BB-1);
    if (time_mask[b*LL + q] != 0) return;        // row fully masked -> uniform

    const int tid  = threadIdx.x;
    const int wave = tid >> 6;
    const int lane = tid & 63;
    const int bl   = lane & 15;                  // A-row-in-tile / B-col-in-tile
    const int bg   = lane >> 4;                  // k-group (8 elems each)

    const int kt = (blockIdx.x*4 + wave) * 16;   // chunk key base
    if (kt > q) return;                          // wave-level exit (no barriers)

    // ---- B fragments (Wt), bt/Wp per-lane channel coefs (L1/L2-hot) ----
    bf16x8 bfrag[4][2];
    float  btv[4], wpv[4];
    #pragma unroll
    for (int n = 0; n < 4; ++n) {
        #pragma unroll
        for (int k = 0; k < 2; ++k) {
            const uint4 raw = *reinterpret_cast<const uint4*>(
                WtT + ((n*16 + bl)*HH + k*32 + bg*8));
            bfrag[n][k] = __builtin_bit_cast(bf16x8, raw);
        }
        btv[n] = bt[n*16 + bl];
        wpv[n] = Wp[n*16 + bl];
    }

    // ---- A fragments straight from global (rows clamped; masked by key<=q) --
    const int ar = min(kt + bl, LL-1);
    const float* src = T + ((size_t)(hb*LL + q)*LL + ar)*HH + bg*8;
    const float4 a0 = *reinterpret_cast<const float4*>(src);
    const float4 a1 = *reinterpret_cast<const float4*>(src + 4);
    const float4 a2 = *reinterpret_cast<const float4*>(src + 32);
    const float4 a3 = *reinterpret_cast<const float4*>(src + 36);

    bf16x8 afrag[2];
    afrag[0] = (bf16x8){(__bf16)a0.x, (__bf16)a0.y, (__bf16)a0.z, (__bf16)a0.w,
                        (__bf16)a1.x, (__bf16)a1.y, (__bf16)a1.z, (__bf16)a1.w};
    afrag[1] = (bf16x8){(__bf16)a2.x, (__bf16)a2.y, (__bf16)a2.z, (__bf16)a2.w,
                        (__bf16)a3.x, (__bf16)a3.y, (__bf16)a3.z, (__bf16)a3.w};

    f32x4 acc[4];
    #pragma unroll
    for (int n = 0; n < 4; ++n) {
        acc[n] = (f32x4){0.f, 0.f, 0.f, 0.f};
        acc[n] = __builtin_amdgcn_mfma_f32_16x16x32_bf16(
                     afrag[0], bfrag[n][0], acc[n], 0, 0, 0);
        acc[n] = __builtin_amdgcn_mfma_f32_16x16x32_bf16(
                     afrag[1], bfrag[n][1], acc[n], 0, 0, 0);
    }

    // ---- epilogue: p[r] = sum_ch relu(S+bt)*Wp ; reduce over 16 col-lanes --
    float p[4] = {0.f, 0.f, 0.f, 0.f};
    #pragma unroll
    for (int n = 0; n < 4; ++n) {
        #pragma unroll
        for (int r = 0; r < 4; ++r)
            p[r] = fmaf(fmaxf(acc[n][r] + btv[n], 0.f), wpv[n], p[r]);
    }
    #pragma unroll
    for (int m = 1; m < 16; m <<= 1) {
        #pragma unroll
        for (int r = 0; r < 4; ++r) p[r] += __shfl_xor(p[r], m, 64);
    }
    if (bl == 0) {
        #pragma unroll
        for (int r = 0; r < 4; ++r) {
            const int key = kt + bg*4 + r;
            if (key <= q)
                Plog[((size_t)hb*LL + q)*LL + key] = p[r];
        }
    }
}

// ---------------------------------------------------------------------------
// Kernel B: QK^T + combine log(sigmoid(p)) + mask + softmax + PV
// one 256-thread block per (hb, q). Reads p from the attn region of d_out
// and overwrites it with the final attention row.
// ---------------------------------------------------------------------------
__global__ __launch_bounds__(256) void attn2_kernel(
    const float* __restrict__ Qs, const float* __restrict__ Ks,
    const float* __restrict__ Vs,
    const int*   __restrict__ time_mask,         // [B, L] int32
    const float* __restrict__ bp,
    float* __restrict__ out, float* __restrict__ attn_out /* = Plog in */)
{
    const int q    = blockIdx.x;
    const int hb   = blockIdx.y;
    const int b    = hb & (BB-1);
    const int head = hb >> 5;
    const int tid  = threadIdx.x;
    const int wave = tid >> 6;
    const int lane = tid & 63;

    __shared__ float sQ[HSS];
    __shared__ float sLogit[LL];
    __shared__ float sRed[8];
    __shared__ float sO[8][HSS];

    if (tid < HSS) sQ[tid] = Qs[(hb*LL + q)*HSS + tid];
    const bool qmask = (time_mask[b*LL + q] != 0);
    const float bp0 = bp[0];
    const float scale = 0.17677669529663687f;    // 1/sqrt(32)
    __syncthreads();

    if (tid < LL) {
        float logit = NEGV;
        if (!qmask && tid <= q) {
            const float4* kr = reinterpret_cast<const float4*>(
                Ks + (hb*LL + tid)*HSS);
            float qk = 0.0f;
            #pragma unroll
            for (int i = 0; i < 8; ++i) {
                const float4 kv = kr[i];
                qk += kv.x*sQ[4*i+0] + kv.y*sQ[4*i+1]
                    + kv.z*sQ[4*i+2] + kv.w*sQ[4*i+3];
            }
            const float p  = attn_out[((size_t)hb*LL + q)*LL + tid];
            const float x  = p + bp0;
            const float ls = -logf(1.0f + expf(-x));   // log(sigmoid(x))
            logit = (qk + ls) * scale;
        }
        sLogit[tid] = logit;
    }
    __syncthreads();

    // ---- softmax over 200 logits ----
    const float v = (tid < LL) ? sLogit[tid] : -INFINITY;
    float mx = v;
    #pragma unroll
    for (int s = 1; s < 64; s <<= 1) mx = fmaxf(mx, __shfl_xor(mx, s, 64));
    if (lane == 0) sRed[wave] = mx;
    __syncthreads();
    const float rowmax = fmaxf(fmaxf(sRed[0], sRed[1]), fmaxf(sRed[2], sRed[3]));

    const float e = (tid < LL) ? expf(v - rowmax) : 0.0f;
    float sm = e;
    #pragma unroll
    for (int s = 1; s < 64; s <<= 1) sm += __shfl_xor(sm, s, 64);
    if (lane == 0) sRed[4 + wave] = sm;
    __syncthreads();
    const float rowsum = sRed[4] + sRed[5] + sRed[6] + sRed[7];
    const float a = e * (1.0f / rowsum);

    __syncthreads();           // sLogit reads above complete
    if (tid < LL) {
        sLogit[tid] = a;
        attn_out[((size_t)hb*LL + q)*LL + tid] = a;
    }
    __syncthreads();

    // ---- out[d] = sum_k a[k] * V[hb][k][d] ----
    {
        const int d = tid & 31;
        const int g = tid >> 5;            // 0..7, 25 keys each
        float acc = 0.0f;
        for (int k = g*25; k < g*25 + 25; ++k)
            acc = fmaf(sLogit[k], Vs[(hb*LL + k)*HSS + d], acc);
        sO[g][d] = acc;
        __syncthreads();
        if (tid < HSS) {
            float o = 0.0f;
            #pragma unroll
            for (int g2 = 0; g2 < 8; ++g2) o += sO[g2][tid];
            out[((size_t)b*LL + q)*HH + head*HSS + tid] = o;
        }
    }
}

// ---------------------------------------------------------------------------
extern "C" void kernel_launch(void* const* d_in, const int* in_sizes, int n_in,
                              void* d_out, int out_size, void* d_ws, size_t ws_size,
                              hipStream_t stream) {
    const float* queries = (const float*)d_in[0];
    const float* keys    = (const float*)d_in[1];
    const float* values  = (const float*)d_in[2];
    const float* T       = (const float*)d_in[3];
    const int*   tmask   = (const int*)d_in[4];
    // d_in[5] = attn_mask (causal triu, computed on the fly -> unused)
    const float* Wq = (const float*)d_in[6];
    const float* bq = (const float*)d_in[7];
    const float* Wk = (const float*)d_in[8];
    const float* bk = (const float*)d_in[9];
    const float* Wv = (const float*)d_in[10];
    const float* bv = (const float*)d_in[11];
    const float* Wt = (const float*)d_in[12];
    const float* bt = (const float*)d_in[13];
    const float* Wp = (const float*)d_in[14];
    const float* bp = (const float*)d_in[15];

    float* Qs = (float*)d_ws;
    float* Ks = Qs + HB*LL*HSS;
    float* Vs = Ks + HB*LL*HSS;
    unsigned short* WtT = (unsigned short*)(Vs + HB*LL*HSS);

    float* out      = (float*)d_out;
    float* attn_out = out + BB*LL*HH;            // doubles as Plog scratch

    prep_kernel<<<16, 256, 0, stream>>>(Wt, WtT);
    proj_kernel<<<BB*LL, 64, 0, stream>>>(queries, keys, values,
                                          Wq, bq, Wk, bk, Wv, bv,
                                          Qs, Ks, Vs);

    dim3 mgrid(4, LL, HB);
    mlp_kernel<<<mgrid, 256, 0, stream>>>(T, tmask, WtT, bt, Wp, attn_out);

    dim3 agrid(LL, HB);
    attn2_kernel<<<agrid, 256, 0, stream>>>(Qs, Ks, Vs, tmask, bp,
                                            out, attn_out);
}

// Round 8
// 241.537 us; speedup vs baseline: 1.1677x; 1.1677x over previous
//
#include <hip/hip_runtime.h>
#include <math.h>

#define BB 32
#define LL 200
#define HH 64
#define HSS 32
#define HB 64
#define NEGV (-4294967295.0f)

typedef __bf16 bf16x8 __attribute__((ext_vector_type(8)));
typedef float f32x4 __attribute__((ext_vector_type(4)));

// ---------------------------------------------------------------------------
// Kernel A: QKV projections into split-head layout  Qs/Ks/Vs [HB][L][HS]
// ---------------------------------------------------------------------------
__global__ __launch_bounds__(64) void proj_kernel(
    const float* __restrict__ q_in, const float* __restrict__ k_in,
    const float* __restrict__ v_in,
    const float* __restrict__ Wq, const float* __restrict__ bq,
    const float* __restrict__ Wk, const float* __restrict__ bk,
    const float* __restrict__ Wv, const float* __restrict__ bv,
    float* __restrict__ Qs, float* __restrict__ Ks, float* __restrict__ Vs)
{
    const int row = blockIdx.x;            // b*L + l
    const int b = row / LL, l = row % LL;
    const int j = threadIdx.x;             // output channel 0..63

    __shared__ float s[3][HH];
    s[0][j] = q_in[row*HH + j];
    s[1][j] = k_in[row*HH + j];
    s[2][j] = v_in[row*HH + j];
    __syncthreads();

    const float* W[3]    = {Wq, Wk, Wv};
    const float* bias[3] = {bq, bk, bv};
    float*       dst[3]  = {Qs, Ks, Vs};

    const int hb  = (j >> 5)*BB + b;                 // head*B + b
    const int idx = (hb*LL + l)*HSS + (j & 31);

    #pragma unroll
    for (int m = 0; m < 3; ++m) {
        float acc = bias[m][j];
        #pragma unroll
        for (int i = 0; i < HH; ++i)
            acc = fmaf(s[m][i], W[m][i*HH + j], acc);
        dst[m][idx] = acc;
    }
}

// ---------------------------------------------------------------------------
// Kernel P: Wt (fp32 [k][n]) -> WtT_bf16 [n][k]  (B-operand, N-major)
// ---------------------------------------------------------------------------
__global__ __launch_bounds__(256) void prep_kernel(
    const float* __restrict__ Wt, unsigned short* __restrict__ WtT)
{
    const int t = blockIdx.x*256 + threadIdx.x;      // t = n*64 + k
    if (t < HH*HH) {
        const int n = t >> 6, k = t & 63;
        const __bf16 h = (__bf16)Wt[k*HH + n];
        WtT[t] = __builtin_bit_cast(unsigned short, h);
    }
}

// ---------------------------------------------------------------------------
// Kernel B: MFMA time-bias MLP over the CAUSAL LOWER TRIANGLE only,
// coalesced staged LDS + 2-deep register pipeline + lgkm-only barriers,
// then QK^T + mask + softmax + PV.
// one 256-thread block per (hb, q); wave w owns key tile {c*64 + w*16}
// ---------------------------------------------------------------------------
__global__ __launch_bounds__(256) void attn_kernel(
    const float* __restrict__ Qs, const float* __restrict__ Ks,
    const float* __restrict__ Vs,
    const float* __restrict__ T,                 // [HB, L, L, H] fp32
    const int*   __restrict__ time_mask,         // [B, L] int32
    const unsigned short* __restrict__ WtT,      // bf16 [n][k]
    const float* __restrict__ bt, const float* __restrict__ Wp,
    const float* __restrict__ bp,
    float* __restrict__ out, float* __restrict__ attn_out)
{
    const int bx   = blockIdx.x;
    // pair small-q with large-q blocks for load balance
    const int q    = (bx & 1) ? (LL - 1 - (bx >> 1)) : (bx >> 1);
    const int hb   = blockIdx.y;
    const int b    = hb & (BB-1);
    const int head = hb >> 5;
    const int tid  = threadIdx.x;
    const int wave = tid >> 6;
    const int lane = tid & 63;
    const int bl   = lane & 15;                  // A-row-in-tile / B-col-in-tile
    const int bg   = lane >> 4;                  // k-group (8 elems each)

    __shared__ __align__(16) unsigned short sA[2][64*HH];  // 2 x 8 KB, swizzled
    __shared__ float sQ[HSS];
    __shared__ float sQK[LL];
    __shared__ float sLogit[LL];
    __shared__ float sRed[8];
    __shared__ float sO[8][HSS];

    const bool qmask = (time_mask[b*LL + q] != 0);
    const int  qeff  = qmask ? -1 : q;           // last live key (-1: none)

    const float* Trow = T + (size_t)(hb*LL + q) * (LL*HH);
    const float4* Trow4 = reinterpret_cast<const float4*>(Trow);

    // row-guarded chunk load: only rows <= qeff are fetched (rest zeros)
#define LOADCHUNK(CUR, c)                                                      \
    {                                                                          \
        _Pragma("unroll")                                                      \
        for (int i = 0; i < 4; ++i) {                                          \
            const int row = i*16 + (tid >> 4);                                 \
            CUR[i] = ((c)*64 + row <= qeff)                                    \
                   ? Trow4[(c)*1024 + i*256 + tid]                             \
                   : make_float4(0.f, 0.f, 0.f, 0.f);                          \
        }                                                                      \
    }

    // ---- issue chunk 0 AND chunk 1 loads first (2-deep pipeline) ----
    float4 va[4], vb[4];
    LOADCHUNK(va, 0)
    LOADCHUNK(vb, 1)

    // ---- B fragments (Wt), bt/Wp per-lane channel coefs ----
    bf16x8 bfrag[4][2];
    float  btv[4], wpv[4];
    #pragma unroll
    for (int n = 0; n < 4; ++n) {
        #pragma unroll
        for (int k = 0; k < 2; ++k) {
            const uint4 raw = *reinterpret_cast<const uint4*>(
                WtT + ((n*16 + bl)*HH + k*32 + bg*8));
            bfrag[n][k] = __builtin_bit_cast(bf16x8, raw);
        }
        btv[n] = bt[n*16 + bl];
        wpv[n] = Wp[n*16 + bl];
    }
    const float bp0 = bp[0];

    if (tid < HSS) sQ[tid] = Qs[(hb*LL + q)*HSS + tid];
    if (tid < LL)  sLogit[tid] = NEGV;           // keys > qeff stay masked
    const float scale = 0.17677669529663687f;    // 1/sqrt(32)

    // sQ/sLogit visible; lgkm-only barrier (global loads stay in flight)
    asm volatile("s_waitcnt lgkmcnt(0)" ::: "memory");
    __builtin_amdgcn_s_barrier();

    // ---- QK^T row (fp32, live keys only) ----
    if (tid <= qeff) {
        const float4* kr = reinterpret_cast<const float4*>(Ks + (hb*LL + tid)*HSS);
        float acc = 0.0f;
        #pragma unroll
        for (int i = 0; i < 8; ++i) {
            const float4 kv = kr[i];
            acc += kv.x*sQ[4*i+0] + kv.y*sQ[4*i+1]
                 + kv.z*sQ[4*i+2] + kv.w*sQ[4*i+3];
        }
        sQK[tid] = acc;     // visible after the barrier inside CHUNK(0)
    }

    // ---- per-chunk macro: pack CUR -> sA[c&1]; reissue; barrier; compute ----
#define PACK_ISSUE_COMPUTE(c, CUR, DO_ISSUE, NC)                               \
    {                                                                          \
        if ((c)*64 <= qeff) {  /* pack chunk c into LDS buffer c&1 */          \
            _Pragma("unroll")                                                  \
            for (int i = 0; i < 4; ++i) {                                      \
                const int g = i*256 + tid;                                     \
                const int row = g >> 4, cf4 = g & 15;                          \
                union { __bf16 h[4]; uint2 u2; } pk;                           \
                pk.h[0] = (__bf16)CUR[i].x; pk.h[1] = (__bf16)CUR[i].y;        \
                pk.h[2] = (__bf16)CUR[i].z; pk.h[3] = (__bf16)CUR[i].w;        \
                const int byteoff = row*128 + ((cf4*8) ^ ((row & 7) << 4));    \
                *reinterpret_cast<uint2*>(                                     \
                    reinterpret_cast<char*>(sA[(c) & 1]) + byteoff) = pk.u2;   \
            }                                                                  \
        }                                                                      \
        if (DO_ISSUE) LOADCHUNK(CUR, NC)  /* WAR: reissue after pack */        \
        /* lgkm-only barrier: ds_writes visible, global loads NOT drained */   \
        asm volatile("s_waitcnt lgkmcnt(0)" ::: "memory");                     \
        __builtin_amdgcn_s_barrier();                                          \
                                                                               \
        const int tileKey = (c)*64 + wave*16;                                  \
        if (tileKey <= qeff) {                                                 \
            const int arow = wave*16 + bl;                                     \
            bf16x8 afrag[2];                                                   \
            _Pragma("unroll")                                                  \
            for (int k = 0; k < 2; ++k) {                                      \
                const int abyte = arow*128 + ((k*64 + bg*16) ^ ((arow & 7) << 4)); \
                const uint4 raw = *reinterpret_cast<const uint4*>(             \
                    reinterpret_cast<const char*>(sA[(c) & 1]) + abyte);       \
                afrag[k] = __builtin_bit_cast(bf16x8, raw);                    \
            }                                                                  \
            f32x4 acc[4];                                                      \
            _Pragma("unroll")                                                  \
            for (int n = 0; n < 4; ++n) {                                      \
                acc[n] = (f32x4){0.f, 0.f, 0.f, 0.f};                          \
                acc[n] = __builtin_amdgcn_mfma_f32_16x16x32_bf16(              \
                             afrag[0], bfrag[n][0], acc[n], 0, 0, 0);          \
                acc[n] = __builtin_amdgcn_mfma_f32_16x16x32_bf16(              \
                             afrag[1], bfrag[n][1], acc[n], 0, 0, 0);          \
            }                                                                  \
            float p[4] = {0.f, 0.f, 0.f, 0.f};                                 \
            _Pragma("unroll")                                                  \
            for (int n = 0; n < 4; ++n) {                                      \
                _Pragma("unroll")                                              \
                for (int r = 0; r < 4; ++r)                                    \
                    p[r] = fmaf(fmaxf(acc[n][r] + btv[n], 0.f), wpv[n], p[r]); \
            }                                                                  \
            _Pragma("unroll")                                                  \
            for (int m = 1; m < 16; m <<= 1) {                                 \
                _Pragma("unroll")                                              \
                for (int r = 0; r < 4; ++r) p[r] += __shfl_xor(p[r], m, 64);   \
            }                                                                  \
            if (bl == 0) {                                                     \
                _Pragma("unroll")                                              \
                for (int r = 0; r < 4; ++r) {                                  \
                    const int key = tileKey + bg*4 + r;                        \
                    if (key <= qeff) {                                         \
                        const float x  = p[r] + bp0;                           \
                        const float ls = -logf(1.0f + expf(-x));               \
                        sLogit[key] = (sQK[key] + ls) * scale;                 \
                    }                                                          \
                }                                                              \
            }                                                                  \
        }                                                                      \
    }

    PACK_ISSUE_COMPUTE(0, va, 1, 2)   // pack c0, reissue va <- chunk 2
    PACK_ISSUE_COMPUTE(1, vb, 1, 3)   // pack c1, reissue vb <- chunk 3
    PACK_ISSUE_COMPUTE(2, va, 0, 0)
    PACK_ISSUE_COMPUTE(3, vb, 0, 0)
#undef PACK_ISSUE_COMPUTE
#undef LOADCHUNK

    __syncthreads();

    // ---- softmax over 200 logits (all-NEG row -> uniform 1/200) ----
    const float v = (tid < LL) ? sLogit[tid] : -INFINITY;
    float mx = v;
    #pragma unroll
    for (int s = 1; s < 64; s <<= 1) mx = fmaxf(mx, __shfl_xor(mx, s, 64));
    if (lane == 0) sRed[wave] = mx;
    __syncthreads();
    const float rowmax = fmaxf(fmaxf(sRed[0], sRed[1]), fmaxf(sRed[2], sRed[3]));

    const float e = (tid < LL) ? expf(v - rowmax) : 0.0f;
    float sm = e;
    #pragma unroll
    for (int s = 1; s < 64; s <<= 1) sm += __shfl_xor(sm, s, 64);
    if (lane == 0) sRed[4 + wave] = sm;
    __syncthreads();
    const float rowsum = sRed[4] + sRed[5] + sRed[6] + sRed[7];
    const float a = e * (1.0f / rowsum);

    __syncthreads();           // sLogit reads above complete
    if (tid < LL) {
        sLogit[tid] = a;
        attn_out[((size_t)(hb*LL + q))*LL + tid] = a;
    }
    __syncthreads();

    // ---- out[d] = sum_k a[k] * V[hb][k][d] ----
    {
        const int d = tid & 31;
        const int g = tid >> 5;            // 0..7, 25 keys each
        float acc = 0.0f;
        for (int k = g*25; k < g*25 + 25; ++k)
            acc = fmaf(sLogit[k], Vs[(hb*LL + k)*HSS + d], acc);
        sO[g][d] = acc;
        __syncthreads();
        if (tid < HSS) {
            float o = 0.0f;
            #pragma unroll
            for (int g2 = 0; g2 < 8; ++g2) o += sO[g2][tid];
            out[((size_t)b*LL + q)*HH + head*HSS + tid] = o;
        }
    }
}

// ---------------------------------------------------------------------------
extern "C" void kernel_launch(void* const* d_in, const int* in_sizes, int n_in,
                              void* d_out, int out_size, void* d_ws, size_t ws_size,
                              hipStream_t stream) {
    const float* queries = (const float*)d_in[0];
    const float* keys    = (const float*)d_in[1];
    const float* values  = (const float*)d_in[2];
    const float* T       = (const float*)d_in[3];
    const int*   tmask   = (const int*)d_in[4];
    // d_in[5] = attn_mask (causal triu, computed on the fly -> unused)
    const float* Wq = (const float*)d_in[6];
    const float* bq = (const float*)d_in[7];
    const float* Wk = (const float*)d_in[8];
    const float* bk = (const float*)d_in[9];
    const float* Wv = (const float*)d_in[10];
    const float* bv = (const float*)d_in[11];
    const float* Wt = (const float*)d_in[12];
    const float* bt = (const float*)d_in[13];
    const float* Wp = (const float*)d_in[14];
    const float* bp = (const float*)d_in[15];

    float* Qs = (float*)d_ws;
    float* Ks = Qs + HB*LL*HSS;
    float* Vs = Ks + HB*LL*HSS;
    unsigned short* WtT = (unsigned short*)(Vs + HB*LL*HSS);

    float* out      = (float*)d_out;
    float* attn_out = out + BB*LL*HH;

    prep_kernel<<<16, 256, 0, stream>>>(Wt, WtT);
    proj_kernel<<<BB*LL, 64, 0, stream>>>(queries, keys, values,
                                          Wq, bq, Wk, bk, Wv, bv,
                                          Qs, Ks, Vs);

    dim3 grid(LL, HB);
    attn_kernel<<<grid, 256, 0, stream>>>(Qs, Ks, Vs, T, tmask,
                                          WtT, bt, Wp, bp, out, attn_out);
}

// Round 9
// 123.731 us; speedup vs baseline: 2.2795x; 1.9521x over previous
//
#include <hip/hip_runtime.h>
#include <math.h>

#define BB 32
#define LL 200
#define HH 64
#define HSS 32
#define HB 64
#define TRI (LL*(LL+1)/2)          // 20100 triangle rows per hb
#define NEGV (-4294967295.0f)

typedef __bf16 bf16x8 __attribute__((ext_vector_type(8)));
typedef float f32x4 __attribute__((ext_vector_type(4)));

// ---------------------------------------------------------------------------
// Kernel A: QKV projections into split-head layout  Qs/Ks/Vs [HB][L][HS]
// ---------------------------------------------------------------------------
__global__ __launch_bounds__(64) void proj_kernel(
    const float* __restrict__ q_in, const float* __restrict__ k_in,
    const float* __restrict__ v_in,
    const float* __restrict__ Wq, const float* __restrict__ bq,
    const float* __restrict__ Wk, const float* __restrict__ bk,
    const float* __restrict__ Wv, const float* __restrict__ bv,
    float* __restrict__ Qs, float* __restrict__ Ks, float* __restrict__ Vs)
{
    const int row = blockIdx.x;            // b*L + l
    const int b = row / LL, l = row % LL;
    const int j = threadIdx.x;             // output channel 0..63

    __shared__ float s[3][HH];
    s[0][j] = q_in[row*HH + j];
    s[1][j] = k_in[row*HH + j];
    s[2][j] = v_in[row*HH + j];
    __syncthreads();

    const float* W[3]    = {Wq, Wk, Wv};
    const float* bias[3] = {bq, bk, bv};
    float*       dst[3]  = {Qs, Ks, Vs};

    const int hb  = (j >> 5)*BB + b;                 // head*B + b
    const int idx = (hb*LL + l)*HSS + (j & 31);

    #pragma unroll
    for (int m = 0; m < 3; ++m) {
        float acc = bias[m][j];
        #pragma unroll
        for (int i = 0; i < HH; ++i)
            acc = fmaf(s[m][i], W[m][i*HH + j], acc);
        dst[m][idx] = acc;
    }
}

// ---------------------------------------------------------------------------
// Kernel P: Wt (fp32 [k][n]) -> WtT_bf16 [n][k]  (B-operand, N-major)
// ---------------------------------------------------------------------------
__global__ __launch_bounds__(256) void prep_kernel(
    const float* __restrict__ Wt, unsigned short* __restrict__ WtT)
{
    const int t = blockIdx.x*256 + threadIdx.x;      // t = n*64 + k
    if (t < HH*HH) {
        const int n = t >> 6, k = t & 63;
        const __bf16 h = (__bf16)Wt[k*HH + n];
        WtT[t] = __builtin_bit_cast(unsigned short, h);
    }
}

// ---------------------------------------------------------------------------
// Kernel M: dense triangle MLP. Each block = 256 consecutive rows of one
// hb's lower triangle {(q,k): k<=q}. Rows resolved to (q,k) once into an
// LDS base table, then 4 uniform passes of coalesced staging -> bf16
// swizzled LDS -> MFMA -> channel-reduce -> scatter p to Plog[hb][q][k].
// 2-deep register pipeline, lgkm-only barriers.
// ---------------------------------------------------------------------------
__global__ __launch_bounds__(256) void mlp_kernel(
    const float* __restrict__ T,                 // [HB, L, L, H] fp32
    const unsigned short* __restrict__ WtT,      // bf16 [n][k]
    const float* __restrict__ bt, const float* __restrict__ Wp,
    float* __restrict__ Plog)                    // [HB*L*L], hb*40000+q*200+k
{
    const int hb   = blockIdx.y;
    const int r0   = blockIdx.x * 256;
    const int tid  = threadIdx.x;
    const int wave = tid >> 6;
    const int lane = tid & 63;
    const int bl   = lane & 15;                  // B-col / C-channel low bits
    const int bg   = lane >> 4;                  // k-group / C-row group

    __shared__ __align__(16) unsigned short sA[2][64*HH];  // 2 x 8 KB
    __shared__ int sBase[256];                   // float4 index of row in T

    // ---- resolve triangle row -> (q,k) -> T row base (once) ----
    {
        int r = r0 + tid; if (r >= TRI) r = TRI - 1;   // clamp (store guarded)
        const float s = sqrtf((float)(8*r + 1));
        int qq = (int)((s - 1.0f) * 0.5f);
        while ((qq + 1)*(qq + 2)/2 <= r) ++qq;         // integer fixup
        while (qq*(qq + 1)/2 > r) --qq;
        const int kk = r - qq*(qq + 1)/2;
        sBase[tid] = ((hb*LL + qq)*LL + kk) << 4;      // float4 units
    }
    __syncthreads();

    const float4* T4 = reinterpret_cast<const float4*>(T);

#define LOADCHUNK(CUR, c)                                                      \
    {                                                                          \
        _Pragma("unroll")                                                      \
        for (int i = 0; i < 4; ++i) {                                          \
            const int g = i*256 + tid;                                         \
            CUR[i] = T4[sBase[(c)*64 + (g >> 4)] + (g & 15)];                  \
        }                                                                      \
    }

    // ---- issue pass 0 AND pass 1 loads first (2-deep pipeline) ----
    float4 va[4], vb[4];
    LOADCHUNK(va, 0)
    LOADCHUNK(vb, 1)

    // ---- B fragments (Wt), bt/Wp per-lane channel coefs (L2-hot) ----
    bf16x8 bfrag[4][2];
    float  btv[4], wpv[4];
    #pragma unroll
    for (int n = 0; n < 4; ++n) {
        #pragma unroll
        for (int k = 0; k < 2; ++k) {
            const uint4 raw = *reinterpret_cast<const uint4*>(
                WtT + ((n*16 + bl)*HH + k*32 + bg*8));
            bfrag[n][k] = __builtin_bit_cast(bf16x8, raw);
        }
        btv[n] = bt[n*16 + bl];
        wpv[n] = Wp[n*16 + bl];
    }

#define PACK_ISSUE_COMPUTE(c, CUR, DO_ISSUE, NC)                               \
    {                                                                          \
        /* pack pass c (waits vmcnt on CUR) into LDS buffer c&1 */             \
        _Pragma("unroll")                                                      \
        for (int i = 0; i < 4; ++i) {                                          \
            const int g = i*256 + tid;                                         \
            const int row = g >> 4, cf4 = g & 15;                              \
            union { __bf16 h[4]; uint2 u2; } pk;                               \
            pk.h[0] = (__bf16)CUR[i].x; pk.h[1] = (__bf16)CUR[i].y;            \
            pk.h[2] = (__bf16)CUR[i].z; pk.h[3] = (__bf16)CUR[i].w;            \
            const int byteoff = row*128 + ((cf4*8) ^ ((row & 7) << 4));        \
            *reinterpret_cast<uint2*>(                                         \
                reinterpret_cast<char*>(sA[(c) & 1]) + byteoff) = pk.u2;       \
        }                                                                      \
        if (DO_ISSUE) LOADCHUNK(CUR, NC)   /* WAR: reissue after pack */       \
        /* lgkm-only barrier: ds ops drained, global loads stay in flight */   \
        asm volatile("s_waitcnt lgkmcnt(0)" ::: "memory");                     \
        __builtin_amdgcn_s_barrier();                                          \
                                                                               \
        const int arow = wave*16 + bl;                                         \
        bf16x8 afrag[2];                                                       \
        _Pragma("unroll")                                                      \
        for (int k = 0; k < 2; ++k) {                                          \
            const int abyte = arow*128 + ((k*64 + bg*16) ^ ((arow & 7) << 4)); \
            const uint4 raw = *reinterpret_cast<const uint4*>(                 \
                reinterpret_cast<const char*>(sA[(c) & 1]) + abyte);           \
            afrag[k] = __builtin_bit_cast(bf16x8, raw);                        \
        }                                                                      \
        f32x4 acc[4];                                                          \
        _Pragma("unroll")                                                      \
        for (int n = 0; n < 4; ++n) {                                          \
            acc[n] = (f32x4){0.f, 0.f, 0.f, 0.f};                              \
            acc[n] = __builtin_amdgcn_mfma_f32_16x16x32_bf16(                  \
                         afrag[0], bfrag[n][0], acc[n], 0, 0, 0);              \
            acc[n] = __builtin_amdgcn_mfma_f32_16x16x32_bf16(                  \
                         afrag[1], bfrag[n][1], acc[n], 0, 0, 0);              \
        }                                                                      \
        float p[4] = {0.f, 0.f, 0.f, 0.f};                                     \
        _Pragma("unroll")                                                      \
        for (int n = 0; n < 4; ++n) {                                          \
            _Pragma("unroll")                                                  \
            for (int r = 0; r < 4; ++r)                                        \
                p[r] = fmaf(fmaxf(acc[n][r] + btv[n], 0.f), wpv[n], p[r]);     \
        }                                                                      \
        _Pragma("unroll")                                                      \
        for (int m = 1; m < 16; m <<= 1) {                                     \
            _Pragma("unroll")                                                  \
            for (int r = 0; r < 4; ++r) p[r] += __shfl_xor(p[r], m, 64);       \
        }                                                                      \
        if (bl == 0) {                                                         \
            _Pragma("unroll")                                                  \
            for (int r = 0; r < 4; ++r) {                                      \
                const int lr = (c)*64 + wave*16 + bg*4 + r;                    \
                if (r0 + lr < TRI)                                             \
                    Plog[sBase[lr] >> 4] = p[r];   /* = hb*40000+q*200+k */    \
            }                                                                  \
        }                                                                      \
    }

    PACK_ISSUE_COMPUTE(0, va, 1, 2)
    PACK_ISSUE_COMPUTE(1, vb, 1, 3)
    PACK_ISSUE_COMPUTE(2, va, 0, 0)
    PACK_ISSUE_COMPUTE(3, vb, 0, 0)
#undef PACK_ISSUE_COMPUTE
#undef LOADCHUNK
}

// ---------------------------------------------------------------------------
// Kernel B: QK^T + combine log(sigmoid(p)) + mask + softmax + PV
// one 256-thread block per (hb, q). Reads p from the attn region of d_out
// and overwrites it with the final attention row.
// ---------------------------------------------------------------------------
__global__ __launch_bounds__(256) void attn2_kernel(
    const float* __restrict__ Qs, const float* __restrict__ Ks,
    const float* __restrict__ Vs,
    const int*   __restrict__ time_mask,         // [B, L] int32
    const float* __restrict__ bp,
    float* __restrict__ out, float* __restrict__ attn_out /* = Plog in */)
{
    const int q    = blockIdx.x;
    const int hb   = blockIdx.y;
    const int b    = hb & (BB-1);
    const int head = hb >> 5;
    const int tid  = threadIdx.x;
    const int wave = tid >> 6;
    const int lane = tid & 63;

    __shared__ float sQ[HSS];
    __shared__ float sLogit[LL];
    __shared__ float sRed[8];
    __shared__ float sO[8][HSS];

    if (tid < HSS) sQ[tid] = Qs[(hb*LL + q)*HSS + tid];
    const bool qmask = (time_mask[b*LL + q] != 0);
    const float bp0 = bp[0];
    const float scale = 0.17677669529663687f;    // 1/sqrt(32)
    __syncthreads();

    if (tid < LL) {
        float logit = NEGV;
        if (!qmask && tid <= q) {
            const float4* kr = reinterpret_cast<const float4*>(
                Ks + (hb*LL + tid)*HSS);
            float qk = 0.0f;
            #pragma unroll
            for (int i = 0; i < 8; ++i) {
                const float4 kv = kr[i];
                qk += kv.x*sQ[4*i+0] + kv.y*sQ[4*i+1]
                    + kv.z*sQ[4*i+2] + kv.w*sQ[4*i+3];
            }
            const float p  = attn_out[((size_t)hb*LL + q)*LL + tid];
            const float x  = p + bp0;
            const float ls = -logf(1.0f + expf(-x));   // log(sigmoid(x))
            logit = (qk + ls) * scale;
        }
        sLogit[tid] = logit;
    }
    __syncthreads();

    // ---- softmax over 200 logits (all-NEG row -> uniform 1/200) ----
    const float v = (tid < LL) ? sLogit[tid] : -INFINITY;
    float mx = v;
    #pragma unroll
    for (int s = 1; s < 64; s <<= 1) mx = fmaxf(mx, __shfl_xor(mx, s, 64));
    if (lane == 0) sRed[wave] = mx;
    __syncthreads();
    const float rowmax = fmaxf(fmaxf(sRed[0], sRed[1]), fmaxf(sRed[2], sRed[3]));

    const float e = (tid < LL) ? expf(v - rowmax) : 0.0f;
    float sm = e;
    #pragma unroll
    for (int s = 1; s < 64; s <<= 1) sm += __shfl_xor(sm, s, 64);
    if (lane == 0) sRed[4 + wave] = sm;
    __syncthreads();
    const float rowsum = sRed[4] + sRed[5] + sRed[6] + sRed[7];
    const float a = e * (1.0f / rowsum);

    __syncthreads();           // sLogit reads above complete
    if (tid < LL) {
        sLogit[tid] = a;
        attn_out[((size_t)hb*LL + q)*LL + tid] = a;
    }
    __syncthreads();

    // ---- out[d] = sum_k a[k] * V[hb][k][d] ----
    {
        const int d = tid & 31;
        const int g = tid >> 5;            // 0..7, 25 keys each
        float acc = 0.0f;
        for (int k = g*25; k < g*25 + 25; ++k)
            acc = fmaf(sLogit[k], Vs[(hb*LL + k)*HSS + d], acc);
        sO[g][d] = acc;
        __syncthreads();
        if (tid < HSS) {
            float o = 0.0f;
            #pragma unroll
            for (int g2 = 0; g2 < 8; ++g2) o += sO[g2][tid];
            out[((size_t)b*LL + q)*HH + head*HSS + tid] = o;
        }
    }
}

// ---------------------------------------------------------------------------
extern "C" void kernel_launch(void* const* d_in, const int* in_sizes, int n_in,
                              void* d_out, int out_size, void* d_ws, size_t ws_size,
                              hipStream_t stream) {
    const float* queries = (const float*)d_in[0];
    const float* keys    = (const float*)d_in[1];
    const float* values  = (const float*)d_in[2];
    const float* T       = (const float*)d_in[3];
    const int*   tmask   = (const int*)d_in[4];
    // d_in[5] = attn_mask (causal triu, computed on the fly -> unused)
    const float* Wq = (const float*)d_in[6];
    const float* bq = (const float*)d_in[7];
    const float* Wk = (const float*)d_in[8];
    const float* bk = (const float*)d_in[9];
    const float* Wv = (const float*)d_in[10];
    const float* bv = (const float*)d_in[11];
    const float* Wt = (const float*)d_in[12];
    const float* bt = (const float*)d_in[13];
    const float* Wp = (const float*)d_in[14];
    const float* bp = (const float*)d_in[15];

    float* Qs = (float*)d_ws;
    float* Ks = Qs + HB*LL*HSS;
    float* Vs = Ks + HB*LL*HSS;
    unsigned short* WtT = (unsigned short*)(Vs + HB*LL*HSS);

    float* out      = (float*)d_out;
    float* attn_out = out + BB*LL*HH;            // doubles as Plog scratch

    prep_kernel<<<16, 256, 0, stream>>>(Wt, WtT);
    proj_kernel<<<BB*LL, 64, 0, stream>>>(queries, keys, values,
                                          Wq, bq, Wk, bk, Wv, bv,
                                          Qs, Ks, Vs);

    dim3 mgrid((TRI + 255) / 256, HB);           // 79 x 64 uniform blocks
    mlp_kernel<<<mgrid, 256, 0, stream>>>(T, WtT, bt, Wp, attn_out);

    dim3 agrid(LL, HB);
    attn2_kernel<<<agrid, 256, 0, stream>>>(Qs, Ks, Vs, tmask, bp,
                                            out, attn_out);
}

// Round 10
// 119.534 us; speedup vs baseline: 2.3595x; 1.0351x over previous
//
#include <hip/hip_runtime.h>
#include <math.h>

#define BB 32
#define LL 200
#define HH 64
#define HSS 32
#define HB 64
#define TRI (LL*(LL+1)/2)          // 20100 triangle rows per hb
#define ROWS 512                   // triangle rows per mlp block
#define NEGV (-4294967295.0f)

typedef __bf16 bf16x8 __attribute__((ext_vector_type(8)));
typedef float f32x4 __attribute__((ext_vector_type(4)));

// ---------------------------------------------------------------------------
// Kernel A: QKV projections into split-head layout  Qs/Ks/Vs [HB][L][HS].
// First 64 blocks additionally convert Wt -> WtT bf16 (fused prep).
// ---------------------------------------------------------------------------
__global__ __launch_bounds__(64) void proj_kernel(
    const float* __restrict__ q_in, const float* __restrict__ k_in,
    const float* __restrict__ v_in,
    const float* __restrict__ Wq, const float* __restrict__ bq,
    const float* __restrict__ Wk, const float* __restrict__ bk,
    const float* __restrict__ Wv, const float* __restrict__ bv,
    const float* __restrict__ Wt, unsigned short* __restrict__ WtT,
    float* __restrict__ Qs, float* __restrict__ Ks, float* __restrict__ Vs)
{
    const int row = blockIdx.x;            // b*L + l
    const int b = row / LL, l = row % LL;
    const int j = threadIdx.x;             // output channel 0..63

    // fused prep: WtT[n*64+k] = bf16(Wt[k*64+n])
    if (blockIdx.x < 64) {
        const int t = blockIdx.x*64 + j;   // t = n*64 + k
        const int n = t >> 6, k = t & 63;
        const __bf16 h = (__bf16)Wt[k*HH + n];
        WtT[t] = __builtin_bit_cast(unsigned short, h);
    }

    __shared__ float s[3][HH];
    s[0][j] = q_in[row*HH + j];
    s[1][j] = k_in[row*HH + j];
    s[2][j] = v_in[row*HH + j];
    __syncthreads();

    const float* W[3]    = {Wq, Wk, Wv};
    const float* bias[3] = {bq, bk, bv};
    float*       dst[3]  = {Qs, Ks, Vs};

    const int hb  = (j >> 5)*BB + b;                 // head*B + b
    const int idx = (hb*LL + l)*HSS + (j & 31);

    #pragma unroll
    for (int m = 0; m < 3; ++m) {
        float acc = bias[m][j];
        #pragma unroll
        for (int i = 0; i < HH; ++i)
            acc = fmaf(s[m][i], W[m][i*HH + j], acc);
        dst[m][idx] = acc;
    }
}

// ---------------------------------------------------------------------------
// Kernel M: dense triangle MLP. Each block = 512 consecutive rows of one
// hb's lower triangle {(q,k): k<=q}. Rows resolved to (q,k) once into an
// LDS base table, then 8 uniform passes of coalesced staging -> bf16
// swizzled LDS -> MFMA -> channel-reduce -> scatter p to Plog[hb][q][k].
// 2-deep register pipeline, lgkm-only barriers.
// ---------------------------------------------------------------------------
__global__ __launch_bounds__(256) void mlp_kernel(
    const float* __restrict__ T,                 // [HB, L, L, H] fp32
    const unsigned short* __restrict__ WtT,      // bf16 [n][k]
    const float* __restrict__ bt, const float* __restrict__ Wp,
    float* __restrict__ Plog)                    // [HB*L*L], hb*40000+q*200+k
{
    const int hb   = blockIdx.y;
    const int r0   = blockIdx.x * ROWS;
    const int tid  = threadIdx.x;
    const int wave = tid >> 6;
    const int lane = tid & 63;
    const int bl   = lane & 15;                  // B-col / C-channel low bits
    const int bg   = lane >> 4;                  // k-group / C-row group

    __shared__ __align__(16) unsigned short sA[2][64*HH];  // 2 x 8 KB
    __shared__ int sBase[ROWS];                  // float4 index of row in T

    // ---- resolve triangle row -> (q,k) -> T row base (once) ----
    #pragma unroll
    for (int j = 0; j < ROWS/256; ++j) {
        int r = r0 + j*256 + tid;
        if (r >= TRI) r = TRI - 1;                     // clamp (store guarded)
        const float s = sqrtf((float)(8*r + 1));
        int qq = (int)((s - 1.0f) * 0.5f);
        while ((qq + 1)*(qq + 2)/2 <= r) ++qq;         // integer fixup
        while (qq*(qq + 1)/2 > r) --qq;
        const int kk = r - qq*(qq + 1)/2;
        sBase[j*256 + tid] = ((hb*LL + qq)*LL + kk) << 4;  // float4 units
    }
    __syncthreads();

    const float4* T4 = reinterpret_cast<const float4*>(T);

#define LOADCHUNK(CUR, c)                                                      \
    {                                                                          \
        _Pragma("unroll")                                                      \
        for (int i = 0; i < 4; ++i) {                                          \
            const int g = i*256 + tid;                                         \
            CUR[i] = T4[sBase[(c)*64 + (g >> 4)] + (g & 15)];                  \
        }                                                                      \
    }

    // ---- issue pass 0 AND pass 1 loads first (2-deep pipeline) ----
    float4 va[4], vb[4];
    LOADCHUNK(va, 0)
    LOADCHUNK(vb, 1)

    // ---- B fragments (Wt), bt/Wp per-lane channel coefs (L2-hot) ----
    bf16x8 bfrag[4][2];
    float  btv[4], wpv[4];
    #pragma unroll
    for (int n = 0; n < 4; ++n) {
        #pragma unroll
        for (int k = 0; k < 2; ++k) {
            const uint4 raw = *reinterpret_cast<const uint4*>(
                WtT + ((n*16 + bl)*HH + k*32 + bg*8));
            bfrag[n][k] = __builtin_bit_cast(bf16x8, raw);
        }
        btv[n] = bt[n*16 + bl];
        wpv[n] = Wp[n*16 + bl];
    }

#define PACK_ISSUE_COMPUTE(c, CUR, DO_ISSUE, NC)                               \
    {                                                                          \
        /* pack pass c (waits vmcnt on CUR) into LDS buffer c&1 */             \
        _Pragma("unroll")                                                      \
        for (int i = 0; i < 4; ++i) {                                          \
            const int g = i*256 + tid;                                         \
            const int row = g >> 4, cf4 = g & 15;                              \
            union { __bf16 h[4]; uint2 u2; } pk;                               \
            pk.h[0] = (__bf16)CUR[i].x; pk.h[1] = (__bf16)CUR[i].y;            \
            pk.h[2] = (__bf16)CUR[i].z; pk.h[3] = (__bf16)CUR[i].w;            \
            const int byteoff = row*128 + ((cf4*8) ^ ((row & 7) << 4));        \
            *reinterpret_cast<uint2*>(                                         \
                reinterpret_cast<char*>(sA[(c) & 1]) + byteoff) = pk.u2;       \
        }                                                                      \
        if (DO_ISSUE) LOADCHUNK(CUR, NC)   /* WAR: reissue after pack */       \
        /* lgkm-only barrier: ds ops drained, global loads stay in flight */   \
        asm volatile("s_waitcnt lgkmcnt(0)" ::: "memory");                     \
        __builtin_amdgcn_s_barrier();                                          \
                                                                               \
        const int arow = wave*16 + bl;                                         \
        bf16x8 afrag[2];                                                       \
        _Pragma("unroll")                                                      \
        for (int k = 0; k < 2; ++k) {                                          \
            const int abyte = arow*128 + ((k*64 + bg*16) ^ ((arow & 7) << 4)); \
            const uint4 raw = *reinterpret_cast<const uint4*>(                 \
                reinterpret_cast<const char*>(sA[(c) & 1]) + abyte);           \
            afrag[k] = __builtin_bit_cast(bf16x8, raw);                        \
        }                                                                      \
        f32x4 acc[4];                                                          \
        _Pragma("unroll")                                                      \
        for (int n = 0; n < 4; ++n) {                                          \
            acc[n] = (f32x4){0.f, 0.f, 0.f, 0.f};                              \
            acc[n] = __builtin_amdgcn_mfma_f32_16x16x32_bf16(                  \
                         afrag[0], bfrag[n][0], acc[n], 0, 0, 0);              \
            acc[n] = __builtin_amdgcn_mfma_f32_16x16x32_bf16(                  \
                         afrag[1], bfrag[n][1], acc[n], 0, 0, 0);              \
        }                                                                      \
        float p[4] = {0.f, 0.f, 0.f, 0.f};                                     \
        _Pragma("unroll")                                                      \
        for (int n = 0; n < 4; ++n) {                                          \
            _Pragma("unroll")                                                  \
            for (int r = 0; r < 4; ++r)                                        \
                p[r] = fmaf(fmaxf(acc[n][r] + btv[n], 0.f), wpv[n], p[r]);     \
        }                                                                      \
        _Pragma("unroll")                                                      \
        for (int m = 1; m < 16; m <<= 1) {                                     \
            _Pragma("unroll")                                                  \
            for (int r = 0; r < 4; ++r) p[r] += __shfl_xor(p[r], m, 64);       \
        }                                                                      \
        if (bl == 0) {                                                         \
            _Pragma("unroll")                                                  \
            for (int r = 0; r < 4; ++r) {                                      \
                const int lr = (c)*64 + wave*16 + bg*4 + r;                    \
                if (r0 + lr < TRI)                                             \
                    Plog[sBase[lr] >> 4] = p[r];   /* = hb*40000+q*200+k */    \
            }                                                                  \
        }                                                                      \
    }

    PACK_ISSUE_COMPUTE(0, va, 1, 2)
    PACK_ISSUE_COMPUTE(1, vb, 1, 3)
    PACK_ISSUE_COMPUTE(2, va, 1, 4)
    PACK_ISSUE_COMPUTE(3, vb, 1, 5)
    PACK_ISSUE_COMPUTE(4, va, 1, 6)
    PACK_ISSUE_COMPUTE(5, vb, 1, 7)
    PACK_ISSUE_COMPUTE(6, va, 0, 0)
    PACK_ISSUE_COMPUTE(7, vb, 0, 0)
#undef PACK_ISSUE_COMPUTE
#undef LOADCHUNK
}

// ---------------------------------------------------------------------------
// Kernel B: QK^T + combine log(sigmoid(p)) + mask + softmax + PV
// one 256-thread block per (hb, q). Reads p from the attn region of d_out
// and overwrites it with the final attention row.
// ---------------------------------------------------------------------------
__global__ __launch_bounds__(256) void attn2_kernel(
    const float* __restrict__ Qs, const float* __restrict__ Ks,
    const float* __restrict__ Vs,
    const int*   __restrict__ time_mask,         // [B, L] int32
    const float* __restrict__ bp,
    float* __restrict__ out, float* __restrict__ attn_out /* = Plog in */)
{
    const int q    = blockIdx.x;
    const int hb   = blockIdx.y;
    const int b    = hb & (BB-1);
    const int head = hb >> 5;
    const int tid  = threadIdx.x;
    const int wave = tid >> 6;
    const int lane = tid & 63;

    __shared__ float sQ[HSS];
    __shared__ float sLogit[LL];
    __shared__ float sRed[8];
    __shared__ float sO[8][HSS];

    const bool qmask = (time_mask[b*LL + q] != 0);
    const bool live  = (tid < LL) && !qmask && (tid <= q);

    // hoisted: issue p load before the barrier (hides under setup)
    float pv = 0.0f;
    if (live) pv = attn_out[((size_t)hb*LL + q)*LL + tid];

    if (tid < HSS) sQ[tid] = Qs[(hb*LL + q)*HSS + tid];
    const float bp0 = bp[0];
    const float scale = 0.17677669529663687f;    // 1/sqrt(32)
    __syncthreads();

    if (tid < LL) {
        float logit = NEGV;
        if (live) {
            const float4* kr = reinterpret_cast<const float4*>(
                Ks + (hb*LL + tid)*HSS);
            float qk = 0.0f;
            #pragma unroll
            for (int i = 0; i < 8; ++i) {
                const float4 kv = kr[i];
                qk += kv.x*sQ[4*i+0] + kv.y*sQ[4*i+1]
                    + kv.z*sQ[4*i+2] + kv.w*sQ[4*i+3];
            }
            const float x  = pv + bp0;
            const float ls = -logf(1.0f + expf(-x));   // log(sigmoid(x))
            logit = (qk + ls) * scale;
        }
        sLogit[tid] = logit;
    }
    __syncthreads();

    // ---- softmax over 200 logits (all-NEG row -> uniform 1/200) ----
    const float v = (tid < LL) ? sLogit[tid] : -INFINITY;
    float mx = v;
    #pragma unroll
    for (int s = 1; s < 64; s <<= 1) mx = fmaxf(mx, __shfl_xor(mx, s, 64));
    if (lane == 0) sRed[wave] = mx;
    __syncthreads();
    const float rowmax = fmaxf(fmaxf(sRed[0], sRed[1]), fmaxf(sRed[2], sRed[3]));

    const float e = (tid < LL) ? expf(v - rowmax) : 0.0f;
    float sm = e;
    #pragma unroll
    for (int s = 1; s < 64; s <<= 1) sm += __shfl_xor(sm, s, 64);
    if (lane == 0) sRed[4 + wave] = sm;
    __syncthreads();
    const float rowsum = sRed[4] + sRed[5] + sRed[6] + sRed[7];
    const float a = e * (1.0f / rowsum);

    __syncthreads();           // sLogit reads above complete
    if (tid < LL) {
        sLogit[tid] = a;
        attn_out[((size_t)hb*LL + q)*LL + tid] = a;
    }
    __syncthreads();

    // ---- out[d] = sum_k a[k] * V[hb][k][d] ----
    {
        const int d = tid & 31;
        const int g = tid >> 5;            // 0..7, 25 keys each
        float acc = 0.0f;
        for (int k = g*25; k < g*25 + 25; ++k)
            acc = fmaf(sLogit[k], Vs[(hb*LL + k)*HSS + d], acc);
        sO[g][d] = acc;
        __syncthreads();
        if (tid < HSS) {
            float o = 0.0f;
            #pragma unroll
            for (int g2 = 0; g2 < 8; ++g2) o += sO[g2][tid];
            out[((size_t)b*LL + q)*HH + head*HSS + tid] = o;
        }
    }
}

// ---------------------------------------------------------------------------
extern "C" void kernel_launch(void* const* d_in, const int* in_sizes, int n_in,
                              void* d_out, int out_size, void* d_ws, size_t ws_size,
                              hipStream_t stream) {
    const float* queries = (const float*)d_in[0];
    const float* keys    = (const float*)d_in[1];
    const float* values  = (const float*)d_in[2];
    const float* T       = (const float*)d_in[3];
    const int*   tmask   = (const int*)d_in[4];
    // d_in[5] = attn_mask (causal triu, computed on the fly -> unused)
    const float* Wq = (const float*)d_in[6];
    const float* bq = (const float*)d_in[7];
    const float* Wk = (const float*)d_in[8];
    const float* bk = (const float*)d_in[9];
    const float* Wv = (const float*)d_in[10];
    const float* bv = (const float*)d_in[11];
    const float* Wt = (const float*)d_in[12];
    const float* bt = (const float*)d_in[13];
    const float* Wp = (const float*)d_in[14];
    const float* bp = (const float*)d_in[15];

    float* Qs = (float*)d_ws;
    float* Ks = Qs + HB*LL*HSS;
    float* Vs = Ks + HB*LL*HSS;
    unsigned short* WtT = (unsigned short*)(Vs + HB*LL*HSS);

    float* out      = (float*)d_out;
    float* attn_out = out + BB*LL*HH;            // doubles as Plog scratch

    proj_kernel<<<BB*LL, 64, 0, stream>>>(queries, keys, values,
                                          Wq, bq, Wk, bk, Wv, bv,
                                          Wt, WtT, Qs, Ks, Vs);

    dim3 mgrid((TRI + ROWS - 1) / ROWS, HB);     // 40 x 64 uniform blocks
    mlp_kernel<<<mgrid, 256, 0, stream>>>(T, WtT, bt, Wp, attn_out);

    dim3 agrid(LL, HB);
    attn2_kernel<<<agrid, 256, 0, stream>>>(Qs, Ks, Vs, tmask, bp,
                                            out, attn_out);
}

// Round 11
// 113.294 us; speedup vs baseline: 2.4895x; 1.0551x over previous
//
#include <hip/hip_runtime.h>
#include <math.h>

#define BB 32
#define LL 200
#define HH 64
#define HSS 32
#define HB 64
#define TRI (LL*(LL+1)/2)          // 20100 triangle rows per hb
#define ROWS 640                   // triangle rows per mlp block (10 passes)
#define NEGV (-4294967295.0f)

typedef __bf16 bf16x8 __attribute__((ext_vector_type(8)));
typedef float f32x4 __attribute__((ext_vector_type(4)));

// ---------------------------------------------------------------------------
// Kernel A: QKV projections into split-head layout  Qs/Ks/Vs [HB][L][HS].
// First 64 blocks additionally convert Wt -> WtT bf16 (fused prep).
// ---------------------------------------------------------------------------
__global__ __launch_bounds__(64) void proj_kernel(
    const float* __restrict__ q_in, const float* __restrict__ k_in,
    const float* __restrict__ v_in,
    const float* __restrict__ Wq, const float* __restrict__ bq,
    const float* __restrict__ Wk, const float* __restrict__ bk,
    const float* __restrict__ Wv, const float* __restrict__ bv,
    const float* __restrict__ Wt, unsigned short* __restrict__ WtT,
    float* __restrict__ Qs, float* __restrict__ Ks, float* __restrict__ Vs)
{
    const int row = blockIdx.x;            // b*L + l
    const int b = row / LL, l = row % LL;
    const int j = threadIdx.x;             // output channel 0..63

    // fused prep: WtT[n*64+k] = bf16(Wt[k*64+n])
    if (blockIdx.x < 64) {
        const int t = blockIdx.x*64 + j;   // t = n*64 + k
        const int n = t >> 6, k = t & 63;
        const __bf16 h = (__bf16)Wt[k*HH + n];
        WtT[t] = __builtin_bit_cast(unsigned short, h);
    }

    __shared__ float s[3][HH];
    s[0][j] = q_in[row*HH + j];
    s[1][j] = k_in[row*HH + j];
    s[2][j] = v_in[row*HH + j];
    __syncthreads();

    const float* W[3]    = {Wq, Wk, Wv};
    const float* bias[3] = {bq, bk, bv};
    float*       dst[3]  = {Qs, Ks, Vs};

    const int hb  = (j >> 5)*BB + b;                 // head*B + b
    const int idx = (hb*LL + l)*HSS + (j & 31);

    #pragma unroll
    for (int m = 0; m < 3; ++m) {
        float acc = bias[m][j];
        #pragma unroll
        for (int i = 0; i < HH; ++i)
            acc = fmaf(s[m][i], W[m][i*HH + j], acc);
        dst[m][idx] = acc;
    }
}

// ---------------------------------------------------------------------------
// Kernel M: dense triangle MLP. Each block = 640 consecutive rows of one
// hb's lower triangle {(q,k): k<=q}; grid 32 x 64 = 2048 blocks (exactly
// 8 per CU, 2 clean occupancy generations at 4 resident blocks/CU).
// Rows resolved to (q,k) once into an LDS base table, then 10 uniform
// passes of coalesced staging -> bf16 swizzled LDS -> MFMA -> reduce ->
// scatter p. 2-deep register pipeline, lgkm-only barriers.
// ---------------------------------------------------------------------------
__global__ __launch_bounds__(256) void mlp_kernel(
    const float* __restrict__ T,                 // [HB, L, L, H] fp32
    const unsigned short* __restrict__ WtT,      // bf16 [n][k]
    const float* __restrict__ bt, const float* __restrict__ Wp,
    float* __restrict__ Plog)                    // [HB*L*L], hb*40000+q*200+k
{
    const int hb   = blockIdx.y;
    const int r0   = blockIdx.x * ROWS;
    const int tid  = threadIdx.x;
    const int wave = tid >> 6;
    const int lane = tid & 63;
    const int bl   = lane & 15;                  // B-col / C-channel low bits
    const int bg   = lane >> 4;                  // k-group / C-row group

    __shared__ __align__(16) unsigned short sA[2][64*HH];  // 2 x 8 KB
    __shared__ int sBase[ROWS];                  // float4 index of row in T

    // ---- resolve triangle row -> (q,k) -> T row base (once) ----
    #pragma unroll
    for (int j = 0; j < 3; ++j) {
        const int rr = j*256 + tid;
        if (rr < ROWS) {
            int r = r0 + rr;
            if (r >= TRI) r = TRI - 1;                 // clamp (store guarded)
            const float s = sqrtf((float)(8*r + 1));
            int qq = (int)((s - 1.0f) * 0.5f);
            while ((qq + 1)*(qq + 2)/2 <= r) ++qq;     // integer fixup
            while (qq*(qq + 1)/2 > r) --qq;
            const int kk = r - qq*(qq + 1)/2;
            sBase[rr] = ((hb*LL + qq)*LL + kk) << 4;   // float4 units
        }
    }
    __syncthreads();

    const float4* T4 = reinterpret_cast<const float4*>(T);

#define LOADCHUNK(CUR, c)                                                      \
    {                                                                          \
        _Pragma("unroll")                                                      \
        for (int i = 0; i < 4; ++i) {                                          \
            const int g = i*256 + tid;                                         \
            CUR[i] = T4[sBase[(c)*64 + (g >> 4)] + (g & 15)];                  \
        }                                                                      \
    }

    // ---- issue pass 0 AND pass 1 loads first (2-deep pipeline) ----
    float4 va[4], vb[4];
    LOADCHUNK(va, 0)
    LOADCHUNK(vb, 1)

    // ---- B fragments (Wt), bt/Wp per-lane channel coefs (L2-hot) ----
    bf16x8 bfrag[4][2];
    float  btv[4], wpv[4];
    #pragma unroll
    for (int n = 0; n < 4; ++n) {
        #pragma unroll
        for (int k = 0; k < 2; ++k) {
            const uint4 raw = *reinterpret_cast<const uint4*>(
                WtT + ((n*16 + bl)*HH + k*32 + bg*8));
            bfrag[n][k] = __builtin_bit_cast(bf16x8, raw);
        }
        btv[n] = bt[n*16 + bl];
        wpv[n] = Wp[n*16 + bl];
    }

#define PACK_ISSUE_COMPUTE(c, CUR, DO_ISSUE, NC)                               \
    {                                                                          \
        /* pack pass c (waits vmcnt on CUR) into LDS buffer c&1 */             \
        _Pragma("unroll")                                                      \
        for (int i = 0; i < 4; ++i) {                                          \
            const int g = i*256 + tid;                                         \
            const int row = g >> 4, cf4 = g & 15;                              \
            union { __bf16 h[4]; uint2 u2; } pk;                               \
            pk.h[0] = (__bf16)CUR[i].x; pk.h[1] = (__bf16)CUR[i].y;            \
            pk.h[2] = (__bf16)CUR[i].z; pk.h[3] = (__bf16)CUR[i].w;            \
            const int byteoff = row*128 + ((cf4*8) ^ ((row & 7) << 4));        \
            *reinterpret_cast<uint2*>(                                         \
                reinterpret_cast<char*>(sA[(c) & 1]) + byteoff) = pk.u2;       \
        }                                                                      \
        if (DO_ISSUE) LOADCHUNK(CUR, NC)   /* WAR: reissue after pack */       \
        /* lgkm-only barrier: ds ops drained, global loads stay in flight */   \
        asm volatile("s_waitcnt lgkmcnt(0)" ::: "memory");                     \
        __builtin_amdgcn_s_barrier();                                          \
                                                                               \
        const int arow = wave*16 + bl;                                         \
        bf16x8 afrag[2];                                                       \
        _Pragma("unroll")                                                      \
        for (int k = 0; k < 2; ++k) {                                          \
            const int abyte = arow*128 + ((k*64 + bg*16) ^ ((arow & 7) << 4)); \
            const uint4 raw = *reinterpret_cast<const uint4*>(                 \
                reinterpret_cast<const char*>(sA[(c) & 1]) + abyte);           \
            afrag[k] = __builtin_bit_cast(bf16x8, raw);                        \
        }                                                                      \
        f32x4 acc[4];                                                          \
        _Pragma("unroll")                                                      \
        for (int n = 0; n < 4; ++n) {                                          \
            acc[n] = (f32x4){0.f, 0.f, 0.f, 0.f};                              \
            acc[n] = __builtin_amdgcn_mfma_f32_16x16x32_bf16(                  \
                         afrag[0], bfrag[n][0], acc[n], 0, 0, 0);              \
            acc[n] = __builtin_amdgcn_mfma_f32_16x16x32_bf16(                  \
                         afrag[1], bfrag[n][1], acc[n], 0, 0, 0);              \
        }                                                                      \
        float p[4] = {0.f, 0.f, 0.f, 0.f};                                     \
        _Pragma("unroll")                                                      \
        for (int n = 0; n < 4; ++n) {                                          \
            _Pragma("unroll")                                                  \
            for (int r = 0; r < 4; ++r)                                        \
                p[r] = fmaf(fmaxf(acc[n][r] + btv[n], 0.f), wpv[n], p[r]);     \
        }                                                                      \
        _Pragma("unroll")                                                      \
        for (int m = 1; m < 16; m <<= 1) {                                     \
            _Pragma("unroll")                                                  \
            for (int r = 0; r < 4; ++r) p[r] += __shfl_xor(p[r], m, 64);       \
        }                                                                      \
        if (bl == 0) {                                                         \
            _Pragma("unroll")                                                  \
            for (int r = 0; r < 4; ++r) {                                      \
                const int lr = (c)*64 + wave*16 + bg*4 + r;                    \
                if (r0 + lr < TRI)                                             \
                    Plog[sBase[lr] >> 4] = p[r];   /* = hb*40000+q*200+k */    \
            }                                                                  \
        }                                                                      \
    }

    PACK_ISSUE_COMPUTE(0, va, 1, 2)
    PACK_ISSUE_COMPUTE(1, vb, 1, 3)
    PACK_ISSUE_COMPUTE(2, va, 1, 4)
    PACK_ISSUE_COMPUTE(3, vb, 1, 5)
    PACK_ISSUE_COMPUTE(4, va, 1, 6)
    PACK_ISSUE_COMPUTE(5, vb, 1, 7)
    PACK_ISSUE_COMPUTE(6, va, 1, 8)
    PACK_ISSUE_COMPUTE(7, vb, 1, 9)
    PACK_ISSUE_COMPUTE(8, va, 0, 0)
    PACK_ISSUE_COMPUTE(9, vb, 0, 0)
#undef PACK_ISSUE_COMPUTE
#undef LOADCHUNK
}

// ---------------------------------------------------------------------------
// Kernel B: QK^T + combine log(sigmoid(p)) + mask + softmax + PV for TWO
// query rows (q, q+100) per block: one K/V load feeds both rows' math.
// grid (100, 64). Reads p from attn region of d_out, overwrites with attn.
// ---------------------------------------------------------------------------
__global__ __launch_bounds__(256) void attn2_kernel(
    const float* __restrict__ Qs, const float* __restrict__ Ks,
    const float* __restrict__ Vs,
    const int*   __restrict__ time_mask,         // [B, L] int32
    const float* __restrict__ bp,
    float* __restrict__ out, float* __restrict__ attn_out /* = Plog in */)
{
    const int q0   = blockIdx.x;                 // 0..99
    const int q1   = q0 + 100;
    const int hb   = blockIdx.y;
    const int b    = hb & (BB-1);
    const int head = hb >> 5;
    const int tid  = threadIdx.x;
    const int wave = tid >> 6;
    const int lane = tid & 63;

    __shared__ float sQ[2][HSS];
    __shared__ float sLogit[2][LL];
    __shared__ float sRed[2][8];
    __shared__ float sO[2][8][HSS];

    const bool qm0 = (time_mask[b*LL + q0] != 0);
    const bool qm1 = (time_mask[b*LL + q1] != 0);
    const bool live0 = (tid < LL) && !qm0 && (tid <= q0);
    const bool live1 = (tid < LL) && !qm1 && (tid <= q1);

    // hoisted: issue p loads before the barrier (hide under setup)
    float pv0 = 0.0f, pv1 = 0.0f;
    if (live0) pv0 = attn_out[((size_t)hb*LL + q0)*LL + tid];
    if (live1) pv1 = attn_out[((size_t)hb*LL + q1)*LL + tid];

    if (tid < 2*HSS)
        sQ[tid >> 5][tid & 31] =
            Qs[(hb*LL + ((tid < HSS) ? q0 : q1))*HSS + (tid & 31)];
    const float bp0 = bp[0];
    const float scale = 0.17677669529663687f;    // 1/sqrt(32)
    __syncthreads();

    if (tid < LL) {
        float l0 = NEGV, l1 = NEGV;
        if (live0 || live1) {
            const float4* kr = reinterpret_cast<const float4*>(
                Ks + (hb*LL + tid)*HSS);
            float qk0 = 0.0f, qk1 = 0.0f;
            #pragma unroll
            for (int i = 0; i < 8; ++i) {
                const float4 kv = kr[i];      // one K load, two dot products
                qk0 += kv.x*sQ[0][4*i+0] + kv.y*sQ[0][4*i+1]
                     + kv.z*sQ[0][4*i+2] + kv.w*sQ[0][4*i+3];
                qk1 += kv.x*sQ[1][4*i+0] + kv.y*sQ[1][4*i+1]
                     + kv.z*sQ[1][4*i+2] + kv.w*sQ[1][4*i+3];
            }
            if (live0) {
                const float x = pv0 + bp0;
                l0 = (qk0 - logf(1.0f + expf(-x))) * scale;
            }
            if (live1) {
                const float x = pv1 + bp0;
                l1 = (qk1 - logf(1.0f + expf(-x))) * scale;
            }
        }
        sLogit[0][tid] = l0;
        sLogit[1][tid] = l1;
    }
    __syncthreads();

    // ---- softmax over 200 logits, both rows (all-NEG -> uniform 1/200) ----
    const float v0 = (tid < LL) ? sLogit[0][tid] : -INFINITY;
    const float v1 = (tid < LL) ? sLogit[1][tid] : -INFINITY;
    float m0 = v0, m1 = v1;
    #pragma unroll
    for (int s = 1; s < 64; s <<= 1) {
        m0 = fmaxf(m0, __shfl_xor(m0, s, 64));
        m1 = fmaxf(m1, __shfl_xor(m1, s, 64));
    }
    if (lane == 0) { sRed[0][wave] = m0; sRed[1][wave] = m1; }
    __syncthreads();
    const float rmax0 = fmaxf(fmaxf(sRed[0][0], sRed[0][1]),
                              fmaxf(sRed[0][2], sRed[0][3]));
    const float rmax1 = fmaxf(fmaxf(sRed[1][0], sRed[1][1]),
                              fmaxf(sRed[1][2], sRed[1][3]));

    const float e0 = (tid < LL) ? expf(v0 - rmax0) : 0.0f;
    const float e1 = (tid < LL) ? expf(v1 - rmax1) : 0.0f;
    float s0 = e0, s1 = e1;
    #pragma unroll
    for (int s = 1; s < 64; s <<= 1) {
        s0 += __shfl_xor(s0, s, 64);
        s1 += __shfl_xor(s1, s, 64);
    }
    if (lane == 0) { sRed[0][4 + wave] = s0; sRed[1][4 + wave] = s1; }
    __syncthreads();
    const float rsum0 = sRed[0][4] + sRed[0][5] + sRed[0][6] + sRed[0][7];
    const float rsum1 = sRed[1][4] + sRed[1][5] + sRed[1][6] + sRed[1][7];
    const float a0 = e0 * (1.0f / rsum0);
    const float a1 = e1 * (1.0f / rsum1);

    if (tid < LL) {
        sLogit[0][tid] = a0;
        sLogit[1][tid] = a1;
        attn_out[((size_t)hb*LL + q0)*LL + tid] = a0;
        attn_out[((size_t)hb*LL + q1)*LL + tid] = a1;
    }
    __syncthreads();

    // ---- out[d] = sum_k a[k] * V[hb][k][d], both rows share the V load ----
    {
        const int d = tid & 31;
        const int g = tid >> 5;            // 0..7, 25 keys each
        float acc0 = 0.0f, acc1 = 0.0f;
        for (int k = g*25; k < g*25 + 25; ++k) {
            const float vv = Vs[(hb*LL + k)*HSS + d];
            acc0 = fmaf(sLogit[0][k], vv, acc0);
            acc1 = fmaf(sLogit[1][k], vv, acc1);
        }
        sO[0][g][d] = acc0;
        sO[1][g][d] = acc1;
        __syncthreads();
        if (tid < 2*HSS) {
            const int which = tid >> 5, d2 = tid & 31;
            float o = 0.0f;
            #pragma unroll
            for (int g2 = 0; g2 < 8; ++g2) o += sO[which][g2][d2];
            out[((size_t)b*LL + (which ? q1 : q0))*HH + head*HSS + d2] = o;
        }
    }
}

// ---------------------------------------------------------------------------
extern "C" void kernel_launch(void* const* d_in, const int* in_sizes, int n_in,
                              void* d_out, int out_size, void* d_ws, size_t ws_size,
                              hipStream_t stream) {
    const float* queries = (const float*)d_in[0];
    const float* keys    = (const float*)d_in[1];
    const float* values  = (const float*)d_in[2];
    const float* T       = (const float*)d_in[3];
    const int*   tmask   = (const int*)d_in[4];
    // d_in[5] = attn_mask (causal triu, computed on the fly -> unused)
    const float* Wq = (const float*)d_in[6];
    const float* bq = (const float*)d_in[7];
    const float* Wk = (const float*)d_in[8];
    const float* bk = (const float*)d_in[9];
    const float* Wv = (const float*)d_in[10];
    const float* bv = (const float*)d_in[11];
    const float* Wt = (const float*)d_in[12];
    const float* bt = (const float*)d_in[13];
    const float* Wp = (const float*)d_in[14];
    const float* bp = (const float*)d_in[15];

    float* Qs = (float*)d_ws;
    float* Ks = Qs + HB*LL*HSS;
    float* Vs = Ks + HB*LL*HSS;
    unsigned short* WtT = (unsigned short*)(Vs + HB*LL*HSS);

    float* out      = (float*)d_out;
    float* attn_out = out + BB*LL*HH;            // doubles as Plog scratch

    proj_kernel<<<BB*LL, 64, 0, stream>>>(queries, keys, values,
                                          Wq, bq, Wk, bk, Wv, bv,
                                          Wt, WtT, Qs, Ks, Vs);

    dim3 mgrid((TRI + ROWS - 1) / ROWS, HB);     // 32 x 64 = 2048 blocks
    mlp_kernel<<<mgrid, 256, 0, stream>>>(T, WtT, bt, Wp, attn_out);

    dim3 agrid(LL/2, HB);                        // 100 x 64, 2 q per block
    attn2_kernel<<<agrid, 256, 0, stream>>>(Qs, Ks, Vs, tmask, bp,
                                            out, attn_out);
}